// Round 1
// baseline (716.375 us; speedup 1.0000x reference)
//
#include <hip/hip_runtime.h>

// Pruned RNN-T loss forward. B=8, T=192, U=193, V=512, PRUNE=5.
// Band per row t: u in [t-5, t+5] ∩ [0, target_len]. Lane d <-> u = t-5+d.

#define NEGV -1.0e30f

constexpr int Bc = 8, Tc = 192, Uc = 193, Vc = 512;
constexpr int Utc = Uc - 1;      // 192
constexpr int ROWS = Tc + 1;     // 193

__device__ __forceinline__ float lae(float a, float b) {
    // logaddexp; exp(-1e30 - x) == 0 exactly, so NEG behaves as -inf.
    float m = fmaxf(a, b);
    float d = fminf(a, b) - m;
    return m + __logf(1.0f + __expf(d));
}

// ws layout: ws[(b*ROWS + t)*32 + d]      = blank term for row t, lane d (d<16)
//            ws[(b*ROWS + t)*32 + 16 + d] = emit gain g for row t, lane d
__global__ void gather_kernel(const float* __restrict__ lp,
                              const int* __restrict__ targets,
                              float* __restrict__ ws,
                              float* __restrict__ out) {
    int tid = blockIdx.x * blockDim.x + threadIdx.x;
    if (tid == 0) out[0] = 0.0f;   // kernel B atomicAdds; harness poisons d_out
    int total = Bc * ROWS * 32;
    if (tid >= total) return;
    int slot = tid & 31;
    int row  = tid >> 5;
    int b = row / ROWS;
    int t = row % ROWS;
    int d = slot & 15;
    int u = t - 5 + d;
    float v = NEGV;
    if (slot < 16) {
        // blank entering row t from row t-1 at same u: lp[b, t-1, u, 0]
        if (t >= 1 && u >= 0 && u <= Uc - 1 && d <= 10)
            v = lp[(((size_t)b * Tc + (t - 1)) * Uc + u) * Vc];
    } else {
        // emit gain g[t][u] = lp[b, t, u-1, targets[b, u-1]] (t<T, u>=1)
        if (t <= Tc - 1 && u >= 1 && u <= Uc - 1 && d <= 10) {
            int tg = targets[b * Utc + (u - 1)];
            v = lp[(((size_t)b * Tc + t) * Uc + (u - 1)) * Vc + tg];
        }
    }
    ws[(size_t)row * 32 + slot] = v;
}

__global__ void __launch_bounds__(64) alpha_kernel(const float* __restrict__ ws,
                                                   const int* __restrict__ logit_len,
                                                   const int* __restrict__ target_len,
                                                   float* __restrict__ out) {
    int b = blockIdx.x;
    int lane = threadIdx.x;                // lanes 0..10 carry the band
    int tlen = target_len[b];
    int llen = logit_len[b];
    int final_lane = tlen - llen + 5;      // guaranteed in [0,10]

    const float* wsb = ws + (size_t)b * ROWS * 32;
    int ls = lane & 15;

    float alpha = NEGV;
    float res = 0.0f;

    // depth-2 prefetch of compact rows (L2-resident after gather_kernel)
    float bl_n = wsb[ls];
    float g_n  = wsb[16 + ls];

    for (int t = 0; t <= Tc; ++t) {
        float bl_c = bl_n, g_c = g_n;
        if (t < Tc) {
            bl_n = wsb[(t + 1) * 32 + ls];
            g_n  = wsb[(t + 1) * 32 + 16 + ls];
        }

        int u = t - 5 + lane;
        bool valid = (u >= 0) && (u <= tlen);

        float base;
        if (t == 0) {
            base = (lane == 5) ? 0.0f : NEGV;   // alpha[0,0] = 0
        } else {
            // prev row band is shifted by one: u maps to lane d+1 of row t-1
            float prevA = __shfl_down(alpha, 1, 64);
            if (lane >= 10) prevA = NEGV;
            base = valid ? (prevA + bl_c) : NEGV;
        }

        // inclusive scan of r[u] = logaddexp(r[u-1] + g[u], base[u]) over 11 lanes
        float g = g_c, r = base;
        #pragma unroll
        for (int s = 1; s <= 8; s <<= 1) {
            float g2 = __shfl_up(g, s, 64);
            float r2 = __shfl_up(r, s, 64);
            if (lane >= s) {
                r = lae(r2 + g, r);
                g = g2 + g;
            }
        }

        alpha = valid ? r : NEGV;

        if (t == llen && lane == final_lane)
            res = -alpha;
    }

    if (lane == final_lane)
        atomicAdd(out, res * (1.0f / Bc));
}

extern "C" void kernel_launch(void* const* d_in, const int* in_sizes, int n_in,
                              void* d_out, int out_size, void* d_ws, size_t ws_size,
                              hipStream_t stream) {
    const float* lp      = (const float*)d_in[0];
    const int* targets   = (const int*)d_in[1];
    const int* llen      = (const int*)d_in[2];
    const int* tlen      = (const int*)d_in[3];
    float* out = (float*)d_out;
    float* ws  = (float*)d_ws;

    int total = Bc * ROWS * 32;
    int blocks = (total + 255) / 256;
    gather_kernel<<<blocks, 256, 0, stream>>>(lp, targets, ws, out);
    alpha_kernel<<<Bc, 64, 0, stream>>>(ws, llen, tlen, out);
}

// Round 2
// 708.817 us; speedup vs baseline: 1.0107x; 1.0107x over previous
//
#include <hip/hip_runtime.h>

// Pruned RNN-T loss forward. B=8, T=192, U=193, V=512, PRUNE=5.
// Band row t: u in [t-5, t+5] ∩ [0, tlen]; lane d <-> u = t-5+d (d in 0..10).
// Single fused kernel: gather band into LDS, then wave0 runs the DP with
// DPP-based 16-lane prefix-logaddexp scans.

#define NEGV -1.0e30f

constexpr int Bc = 8, Tc = 192, Uc = 193, Vc = 512;
constexpr int Utc = Uc - 1;   // 192
constexpr int ROWS = Tc + 1;  // 193

// result = valid_src ? src[lane mapped by CTRL] : old   (bound_ctrl=0)
template <int CTRL>
__device__ __forceinline__ float dppf(float old, float x) {
    return __int_as_float(__builtin_amdgcn_update_dpp(
        __float_as_int(old), __float_as_int(x), CTRL, 0xF, 0xF, false));
}
// row_shr:N (lane i <- i-N within 16-lane row): CTRL = 0x110+N
// row_shl:1 (lane i <- i+1 within row):         CTRL = 0x101

__device__ __forceinline__ float lae(float a, float b) {
    // logaddexp; exp(-1e30 - x) == 0 exactly in fp32, so NEGV acts as -inf.
    float m = fmaxf(a, b);
    float d = fminf(a, b) - m;
    return m + __logf(1.0f + __expf(d));
}

__device__ __forceinline__ float prefix_sum16(float g) {
    g += dppf<0x111>(0.0f, g);
    g += dppf<0x112>(0.0f, g);
    g += dppf<0x114>(0.0f, g);
    g += dppf<0x118>(0.0f, g);
    return g;
}

__global__ void __launch_bounds__(512) rnnt_fused_kernel(
        const float* __restrict__ lp, const int* __restrict__ targets,
        const int* __restrict__ logit_len, const int* __restrict__ target_len,
        float* __restrict__ out) {
    __shared__ float2 rowbuf[ROWS * 16];  // [t][d] = {blank entering (t,u), emit gain g(t,u)}

    const int b = blockIdx.x;
    const int tlen = target_len[b];
    const int llen = logit_len[b];
    const int nrows = llen + 1;

    // ---- gather band cells straight into LDS (all 512 threads) ----
    for (int idx = threadIdx.x; idx < nrows * 16; idx += 512) {
        int t = idx >> 4, d = idx & 15;
        int u = t - 5 + d;
        float bl = NEGV;  // blank move into (t,u) from (t-1,u): lp[b,t-1,u,0]
        float g = 0.0f;   // emit gain into (t,u) from (t,u-1): lp[b,t,u-1,tgt[u-1]]
                          // invalid g stored as 0: those chains start at NEG bases.
        if (d <= 10 && u >= 0 && u <= Uc - 1 && t >= 1)
            bl = lp[(((size_t)b * Tc + (t - 1)) * Uc + u) * Vc];
        if (d <= 10 && u >= 1 && u <= Uc - 1 && t <= Tc - 1)
            g = lp[(((size_t)b * Tc + t) * Uc + (u - 1)) * Vc + targets[b * Utc + (u - 1)]];
        rowbuf[idx] = make_float2(bl, g);
    }
    __syncthreads();
    if (threadIdx.x >= 64) return;

    // ---- sequential DP, wave 0; lanes 0..15 hold the band (0..10 live) ----
    const int lane = threadIdx.x;
    const int ls = lane & 15;

    float alpha = NEGV;
    float2 cur = rowbuf[ls];           // row 0
    float G = prefix_sum16(cur.y);     // prefix sums of emit gains (off critical path)
    float2 nxt;

    for (int t = 0; t <= llen; ++t) {
        if (t < llen) nxt = rowbuf[(t + 1) * 16 + ls];  // prefetch next row

        float base;
        if (t == 0) {
            base = (lane == 5) ? 0.0f : NEGV;  // alpha[0,0] = 0 at u=0 (d=5)
        } else {
            float prevA = dppf<0x101>(NEGV, alpha);  // prev row, band shifted by 1
            base = prevA + cur.x;
        }

        float r;
        if (t == Tc) {
            r = base;  // row T: emit gains are -inf in the reference -> no chain
        } else {
            // r[d] = G[d] + prefix-logaddexp_{k<=d}(base[k]-G[k])
            float s = base - G;
            s = lae(dppf<0x111>(NEGV, s), s);
            s = lae(dppf<0x112>(NEGV, s), s);
            s = lae(dppf<0x114>(NEGV, s), s);
            s = lae(dppf<0x118>(NEGV, s), s);
            r = s + G;
        }

        int u = t - 5 + lane;
        bool valid = (lane <= 10) && (u >= 0) && (u <= tlen);
        alpha = valid ? r : NEGV;

        if (t < llen) { cur = nxt; G = prefix_sum16(cur.y); }
    }

    // alpha now holds row llen; terminal cell u=tlen is lane tlen-llen+5 (in [2,8])
    if (lane == tlen - llen + 5)
        atomicAdd(out, alpha * (-1.0f / (float)Bc));
}

extern "C" void kernel_launch(void* const* d_in, const int* in_sizes, int n_in,
                              void* d_out, int out_size, void* d_ws, size_t ws_size,
                              hipStream_t stream) {
    const float* lp    = (const float*)d_in[0];
    const int* targets = (const int*)d_in[1];
    const int* llen    = (const int*)d_in[2];
    const int* tlen    = (const int*)d_in[3];
    float* out = (float*)d_out;

    hipMemsetAsync(out, 0, sizeof(float) * out_size, stream);
    rnnt_fused_kernel<<<Bc, 512, 0, stream>>>(lp, targets, llen, tlen, out);
}

// Round 3
// 685.106 us; speedup vs baseline: 1.0456x; 1.0346x over previous
//
#include <hip/hip_runtime.h>

// Pruned RNN-T loss forward. B=8, T=192, U=193, V=512, PRUNE=5.
// Band row t: u in [t-5, t+5] ∩ [0, tlen]; lane d <-> u = t-5+d (d in 0..10).
// Fused: gather band into LDS (1024 thr), wave0 runs DP with DPP 16-lane
// prefix-logaddexp scans in log2 domain (inputs pre-scaled by log2(e)).

#define NEGV -1.0e30f
#define LOG2E 1.4426950408889634f
#define LN2   0.6931471805599453f

constexpr int Bc = 8, Tc = 192, Uc = 193, Vc = 512;
constexpr int Utc = Uc - 1;   // 192
constexpr int ROWS = Tc + 1;  // 193

#if __has_builtin(__builtin_amdgcn_exp2f)
#define EXP2(x) __builtin_amdgcn_exp2f(x)
#else
#define EXP2(x) __expf((x) * LN2)
#endif
#if __has_builtin(__builtin_amdgcn_logf)
#define LOG2(x) __builtin_amdgcn_logf(x)
#else
#define LOG2(x) (__logf(x) * LOG2E)
#endif

// result = valid_src ? src[lane mapped by CTRL] : old   (bound_ctrl=0)
template <int CTRL>
__device__ __forceinline__ float dppf(float old, float x) {
    return __int_as_float(__builtin_amdgcn_update_dpp(
        __float_as_int(old), __float_as_int(x), CTRL, 0xF, 0xF, false));
}
// row_shr:N (lane i <- i-N within 16-lane row): CTRL = 0x110+N
// row_shl:1 (lane i <- i+1 within row):         CTRL = 0x101

// log2-domain logaddexp: values are ln(p)*log2(e); exp2(-1.4e30-x)==0 exactly.
__device__ __forceinline__ float lae2(float a, float b) {
    float m = fmaxf(a, b);
    float d = fminf(a, b) - m;
    return m + LOG2(1.0f + EXP2(d));
}

__device__ __forceinline__ float prefix_sum16(float g) {
    g += dppf<0x111>(0.0f, g);
    g += dppf<0x112>(0.0f, g);
    g += dppf<0x114>(0.0f, g);
    g += dppf<0x118>(0.0f, g);
    return g;
}

__global__ void __launch_bounds__(1024) rnnt_fused_kernel(
        const float* __restrict__ lp, const int* __restrict__ targets,
        const int* __restrict__ logit_len, const int* __restrict__ target_len,
        float* __restrict__ out) {
    __shared__ float2 rowbuf[ROWS * 16];  // [t][d] = {blank into (t,u), emit gain g(t,u)} * log2e

    const int b = blockIdx.x;
    const int tlen = target_len[b];
    const int llen = logit_len[b];
    const int nrows = llen + 1;

    // ---- gather band cells straight into LDS (all 1024 threads) ----
    for (int idx = threadIdx.x; idx < nrows * 16; idx += 1024) {
        int t = idx >> 4, d = idx & 15;
        int u = t - 5 + d;
        float bl = NEGV;  // blank move into (t,u) from (t-1,u): lp[b,t-1,u,0]
        float g = 0.0f;   // emit gain into (t,u) from (t,u-1): lp[b,t,u-1,tgt[u-1]]
                          // invalid g stored as 0: those chains start at NEG bases.
        if (d <= 10 && u >= 0 && u <= Uc - 1 && t >= 1)
            bl = lp[(((size_t)b * Tc + (t - 1)) * Uc + u) * Vc] * LOG2E;
        if (d <= 10 && u >= 1 && u <= Uc - 1 && t <= Tc - 1)
            g = lp[(((size_t)b * Tc + t) * Uc + (u - 1)) * Vc + targets[b * Utc + (u - 1)]] * LOG2E;
        rowbuf[idx] = make_float2(bl, g);
    }
    __syncthreads();
    if (threadIdx.x >= 64) return;

    // ---- sequential DP, wave 0; lanes 0..15 hold the band (0..10 live) ----
    const int lane = threadIdx.x;
    const int ls = lane & 15;

    float alpha = NEGV;
    float2 cur = rowbuf[ls];           // row 0
    float G = prefix_sum16(cur.y);     // prefix sums of emit gains (off critical path)
    float2 nxt;

    for (int t = 0; t <= llen; ++t) {
        if (t < llen) nxt = rowbuf[(t + 1) * 16 + ls];  // prefetch next row

        float base;
        if (t == 0) {
            base = (lane == 5) ? 0.0f : NEGV;  // alpha[0,0] = 0 at u=0 (d=5)
        } else {
            float prevA = dppf<0x101>(NEGV, alpha);  // prev row, band shifted by 1
            base = prevA + cur.x;
        }

        float r;
        if (t == Tc) {
            r = base;  // row T: emit gains are -inf in the reference -> no chain
        } else {
            // r[d] = G[d] + prefix-logaddexp_{k<=d}(base[k]-G[k])
            float s = base - G;
            s = lae2(dppf<0x111>(NEGV, s), s);
            s = lae2(dppf<0x112>(NEGV, s), s);
            s = lae2(dppf<0x114>(NEGV, s), s);
            s = lae2(dppf<0x118>(NEGV, s), s);
            r = s + G;
        }

        int u = t - 5 + lane;
        bool valid = (lane <= 10) && (u >= 0) && (u <= tlen);
        alpha = valid ? r : NEGV;

        if (t < llen) { cur = nxt; G = prefix_sum16(cur.y); }
    }

    // alpha holds row llen; terminal cell u=tlen lives in lane tlen-llen+5
    if (lane == tlen - llen + 5)
        atomicAdd(out, alpha * (-LN2 / (float)Bc));  // back to natural log + mean
}

extern "C" void kernel_launch(void* const* d_in, const int* in_sizes, int n_in,
                              void* d_out, int out_size, void* d_ws, size_t ws_size,
                              hipStream_t stream) {
    const float* lp    = (const float*)d_in[0];
    const int* targets = (const int*)d_in[1];
    const int* llen    = (const int*)d_in[2];
    const int* tlen    = (const int*)d_in[3];
    float* out = (float*)d_out;

    hipMemsetAsync(out, 0, sizeof(float) * out_size, stream);
    rnnt_fused_kernel<<<Bc, 1024, 0, stream>>>(lp, targets, llen, tlen, out);
}